// Round 4
// baseline (261.135 us; speedup 1.0000x reference)
//
#include <hip/hip_runtime.h>

#define D 128
#define NBINS_MAX 10016 // max nodes supported by single-block LDS scan
#define GM 32           // gemm rows per block

// ---------------- degree count via L2-resident global atomics ----------------
// in_deg/out_deg are 40KB each -> L2-resident; ~128 increments per counter
// spread across the kernel's lifetime -> negligible contention.
__global__ __launch_bounds__(256) void deg_kernel(const int* __restrict__ src, const int* __restrict__ dst,
                                                  int* __restrict__ in_deg, int* __restrict__ out_deg, int E) {
    int i = blockIdx.x * 256 + threadIdx.x;
    int stride = gridDim.x * 256;
    for (int e = i; e < E; e += stride) {
        atomicAdd(&in_deg[dst[e]], 1);
        atomicAdd(&out_deg[src[e]], 1);
    }
}

// ---------------- single block: scan in_deg -> row_start/cursor; norms ----------------
__global__ __launch_bounds__(1024) void scan_kernel(const int* __restrict__ in_deg, const int* __restrict__ out_deg,
                                                    int* __restrict__ row_start, int* __restrict__ cursor,
                                                    float* __restrict__ norm_src, float* __restrict__ norm_dst,
                                                    int n) {
    __shared__ int buf[NBINS_MAX];
    __shared__ int part[1024];
    int t = threadIdx.x;
    for (int i = t; i < n; i += 1024) buf[i] = in_deg[i];
    __syncthreads();
    int ipt = (n + 1023) / 1024;
    int lo = min(t * ipt, n), hi = min(lo + ipt, n);
    int s = 0;
    for (int i = lo; i < hi; ++i) s += buf[i];
    part[t] = s;
    __syncthreads();
    for (int off = 1; off < 1024; off <<= 1) {
        int v = 0;
        if (t >= off) v = part[t - off];
        __syncthreads();
        if (t >= off) part[t] += v;
        __syncthreads();
    }
    int run = part[t] - s;
    for (int i = lo; i < hi; ++i) {
        int v = buf[i];
        buf[i] = run;
        run += v;
    }
    __syncthreads();
    for (int i = t; i < n; i += 1024) {
        int rs = buf[i];
        row_start[i] = rs;
        cursor[i] = rs;
        norm_dst[i] = rsqrtf(fmaxf((float)in_deg[i], 1.0f));
        norm_src[i] = rsqrtf(fmaxf((float)out_deg[i], 1.0f));
    }
    if (t == 0) row_start[n] = part[1023];
}

// ---------------- CSR fill via global atomic cursor (order within row arbitrary) ----------------
// Record weight = ew[e] * norm_src[src[e]]  (layer-invariant; folds the src-norm).
// cursor is 40KB -> L2-resident atomics with return; ~64 per counter.
__global__ __launch_bounds__(256) void fill_kernel(const int* __restrict__ src, const int* __restrict__ dst,
                                                   const float* __restrict__ ew, const float* __restrict__ ns,
                                                   int* __restrict__ cursor, int2* __restrict__ sorted, int E) {
    int i = blockIdx.x * 256 + threadIdx.x;
    int stride = gridDim.x * 256;
    for (int e = i; e < E; e += stride) {
        int d = dst[e];
        int slot = atomicAdd(&cursor[d], 1);
        int s = src[e];
        int2 rec;
        rec.x = s;
        rec.y = __float_as_int(ew[e] * ns[s]);
        sorted[slot] = rec;
    }
}

// ---------------- XCD-partitioned aggregation, software-pipelined (R1 form) ----------------
// blockIdx%8 -> XCD slot. Slots 0-3 handle feature chunk [0,64), slots 4-7
// chunk [64,128); each slot owns one node quad -> per-XCD hot x-slice 2.56MB,
// L2-resident. One wave per (node, chunk); lane = feature. 8 record-paired
// gathers in flight, next batch's records prefetched ahead of the gathers.
__global__ __launch_bounds__(256) void agg_kernel(const float* __restrict__ h, const int* __restrict__ row_start,
                                                  const int2* __restrict__ sorted, float* __restrict__ out,
                                                  int n, int qn) {
    int slot  = blockIdx.x & 7;
    int g     = blockIdx.x >> 3;
    int chunk = slot >> 2;         // 0 or 1
    int quad  = slot & 3;          // node quad
    int wave  = threadIdx.x >> 6;
    int lane  = threadIdx.x & 63;
    int node  = quad * qn + g * 4 + wave;
    int hiN   = min((quad + 1) * qn, n);
    if (node >= hiN) return;
    const float* hc = h + chunk * 64 + lane;
    int beg = __builtin_amdgcn_readfirstlane(row_start[node]);
    int end = __builtin_amdgcn_readfirstlane(row_start[node + 1]);
    float acc = 0.f;
    int s = beg;
    if (s < end && (s & 1)) {   // peel to even index -> 16B-aligned int4 record loads
        int2 rr = sorted[s];
        acc = fmaf(__int_as_float(rr.y), hc[rr.x << 7], acc);
        ++s;
    }
    int4 p0, p1, p2, p3;
    if (s + 8 <= end) {
        p0 = *(const int4*)(sorted + s);
        p1 = *(const int4*)(sorted + s + 2);
        p2 = *(const int4*)(sorted + s + 4);
        p3 = *(const int4*)(sorted + s + 6);
    }
    for (; s + 16 <= end; s += 8) {
        // prefetch records for the next iteration (independent of current gathers)
        int4 q0 = *(const int4*)(sorted + s + 8);
        int4 q1 = *(const int4*)(sorted + s + 10);
        int4 q2 = *(const int4*)(sorted + s + 12);
        int4 q3 = *(const int4*)(sorted + s + 14);
        float x0 = hc[p0.x << 7];
        float x1 = hc[p0.z << 7];
        float x2 = hc[p1.x << 7];
        float x3 = hc[p1.z << 7];
        float x4 = hc[p2.x << 7];
        float x5 = hc[p2.z << 7];
        float x6 = hc[p3.x << 7];
        float x7 = hc[p3.z << 7];
        acc = fmaf(__int_as_float(p0.y), x0, acc);
        acc = fmaf(__int_as_float(p0.w), x1, acc);
        acc = fmaf(__int_as_float(p1.y), x2, acc);
        acc = fmaf(__int_as_float(p1.w), x3, acc);
        acc = fmaf(__int_as_float(p2.y), x4, acc);
        acc = fmaf(__int_as_float(p2.w), x5, acc);
        acc = fmaf(__int_as_float(p3.y), x6, acc);
        acc = fmaf(__int_as_float(p3.w), x7, acc);
        p0 = q0; p1 = q1; p2 = q2; p3 = q3;
    }
    if (s + 8 <= end) {   // drain the pipelined batch
        float x0 = hc[p0.x << 7];
        float x1 = hc[p0.z << 7];
        float x2 = hc[p1.x << 7];
        float x3 = hc[p1.z << 7];
        float x4 = hc[p2.x << 7];
        float x5 = hc[p2.z << 7];
        float x6 = hc[p3.x << 7];
        float x7 = hc[p3.z << 7];
        acc = fmaf(__int_as_float(p0.y), x0, acc);
        acc = fmaf(__int_as_float(p0.w), x1, acc);
        acc = fmaf(__int_as_float(p1.y), x2, acc);
        acc = fmaf(__int_as_float(p1.w), x3, acc);
        acc = fmaf(__int_as_float(p2.y), x4, acc);
        acc = fmaf(__int_as_float(p2.w), x5, acc);
        acc = fmaf(__int_as_float(p3.y), x6, acc);
        acc = fmaf(__int_as_float(p3.w), x7, acc);
        s += 8;
    }
    for (; s + 2 <= end; s += 2) {
        int4 p = *(const int4*)(sorted + s);
        acc = fmaf(__int_as_float(p.y), hc[p.x << 7], acc);
        acc = fmaf(__int_as_float(p.w), hc[p.z << 7], acc);
    }
    if (s < end) {
        int2 rr = sorted[s];
        acc = fmaf(__int_as_float(rr.y), hc[rr.x << 7], acc);
    }
    out[((size_t)node << 7) + chunk * 64 + lane] = acc;
}

// ---------------- GEMM + epilogue: out = relu((A@W)*norm_dst[:,None] + b) ----------------
// 32-row tile, A staged TRANSPOSED in LDS (sAT[k][r], stride 34 -> broadcast-
// friendly float2 reads). 256 threads: tx=tid&15 (8 cols), ty=tid>>4 (2 rows).
__global__ __launch_bounds__(256) void gemm_kernel(const float* __restrict__ A, const float* __restrict__ W,
                                                   const float* __restrict__ bias, const float* __restrict__ norm_dst,
                                                   float* __restrict__ out, int n) {
    __shared__ __align__(16) float sAT[D][GM + 2];   // stride 34: float2 reads stay 8B-aligned
    int tid = threadIdx.x;
    int row0 = blockIdx.x * GM;
    for (int i = tid; i < GM * 32; i += 256) {
        int r = i >> 5;          // 0..31
        int kq = i & 31;         // k-quad
        int rr = row0 + r;
        float4 v = make_float4(0.f, 0.f, 0.f, 0.f);
        if (rr < n) v = *(const float4*)(A + (size_t)rr * D + kq * 4);
        sAT[kq * 4 + 0][r] = v.x;
        sAT[kq * 4 + 1][r] = v.y;
        sAT[kq * 4 + 2][r] = v.z;
        sAT[kq * 4 + 3][r] = v.w;
    }
    __syncthreads();
    int tx = tid & 15;
    int ty = tid >> 4;
    int c0 = tx * 8;
    int r0 = ty * 2;
    float acc0[8], acc1[8];
#pragma unroll
    for (int j = 0; j < 8; ++j) { acc0[j] = 0.f; acc1[j] = 0.f; }
    const float* Wk = W + c0;
#pragma unroll 4
    for (int k = 0; k < D; ++k) {
        float2 a = *(const float2*)&sAT[k][r0];
        float4 w0 = *(const float4*)(Wk);
        float4 w1 = *(const float4*)(Wk + 4);
        Wk += D;
        acc0[0] = fmaf(a.x, w0.x, acc0[0]);
        acc0[1] = fmaf(a.x, w0.y, acc0[1]);
        acc0[2] = fmaf(a.x, w0.z, acc0[2]);
        acc0[3] = fmaf(a.x, w0.w, acc0[3]);
        acc0[4] = fmaf(a.x, w1.x, acc0[4]);
        acc0[5] = fmaf(a.x, w1.y, acc0[5]);
        acc0[6] = fmaf(a.x, w1.z, acc0[6]);
        acc0[7] = fmaf(a.x, w1.w, acc0[7]);
        acc1[0] = fmaf(a.y, w0.x, acc1[0]);
        acc1[1] = fmaf(a.y, w0.y, acc1[1]);
        acc1[2] = fmaf(a.y, w0.z, acc1[2]);
        acc1[3] = fmaf(a.y, w0.w, acc1[3]);
        acc1[4] = fmaf(a.y, w1.x, acc1[4]);
        acc1[5] = fmaf(a.y, w1.y, acc1[5]);
        acc1[6] = fmaf(a.y, w1.z, acc1[6]);
        acc1[7] = fmaf(a.y, w1.w, acc1[7]);
    }
    int r = row0 + r0;
    if (r < n) {
        float nd = norm_dst[r];
        float4 o0, o1;
        o0.x = fmaxf(fmaf(acc0[0], nd, bias[c0 + 0]), 0.f);
        o0.y = fmaxf(fmaf(acc0[1], nd, bias[c0 + 1]), 0.f);
        o0.z = fmaxf(fmaf(acc0[2], nd, bias[c0 + 2]), 0.f);
        o0.w = fmaxf(fmaf(acc0[3], nd, bias[c0 + 3]), 0.f);
        o1.x = fmaxf(fmaf(acc0[4], nd, bias[c0 + 4]), 0.f);
        o1.y = fmaxf(fmaf(acc0[5], nd, bias[c0 + 5]), 0.f);
        o1.z = fmaxf(fmaf(acc0[6], nd, bias[c0 + 6]), 0.f);
        o1.w = fmaxf(fmaf(acc0[7], nd, bias[c0 + 7]), 0.f);
        *(float4*)(out + (size_t)r * D + c0) = o0;
        *(float4*)(out + (size_t)r * D + c0 + 4) = o1;
    }
    r = row0 + r0 + 1;
    if (r < n) {
        float nd = norm_dst[r];
        float4 o0, o1;
        o0.x = fmaxf(fmaf(acc1[0], nd, bias[c0 + 0]), 0.f);
        o0.y = fmaxf(fmaf(acc1[1], nd, bias[c0 + 1]), 0.f);
        o0.z = fmaxf(fmaf(acc1[2], nd, bias[c0 + 2]), 0.f);
        o0.w = fmaxf(fmaf(acc1[3], nd, bias[c0 + 3]), 0.f);
        o1.x = fmaxf(fmaf(acc1[4], nd, bias[c0 + 4]), 0.f);
        o1.y = fmaxf(fmaf(acc1[5], nd, bias[c0 + 5]), 0.f);
        o1.z = fmaxf(fmaf(acc1[6], nd, bias[c0 + 6]), 0.f);
        o1.w = fmaxf(fmaf(acc1[7], nd, bias[c0 + 7]), 0.f);
        *(float4*)(out + (size_t)r * D + c0) = o0;
        *(float4*)(out + (size_t)r * D + c0 + 4) = o1;
    }
}

extern "C" void kernel_launch(void* const* d_in, const int* in_sizes, int n_in,
                              void* d_out, int out_size, void* d_ws, size_t ws_size,
                              hipStream_t stream) {
    const float* x  = (const float*)d_in[0];
    const float* ew = (const float*)d_in[1];
    const float* W0 = (const float*)d_in[2];
    const float* b0 = (const float*)d_in[3];
    const float* W1 = (const float*)d_in[4];
    const float* b1 = (const float*)d_in[5];
    const int* src  = (const int*)d_in[6];
    const int* dst  = (const int*)d_in[7];
    float* out = (float*)d_out;

    int n = in_sizes[0] / D;   // 10000
    int E = in_sizes[6];       // 640000
    if (n <= 0 || E <= 0) return;

    char* ws = (char*)d_ws;
    size_t off = 0;
    auto alloc = [&](size_t bytes) -> void* {
        void* p = ws + off;
        off = (off + bytes + 255) & ~(size_t)255;
        return p;
    };
    int* row_start  = (int*)alloc(((size_t)n + 1) * 4);
    int* cursor     = (int*)alloc((size_t)n * 4);
    int* deg_buf    = (int*)alloc((size_t)2 * n * 4);   // in_deg | out_deg, one memset
    float* norm_src = (float*)alloc((size_t)n * 4);
    float* norm_dst = (float*)alloc((size_t)n * 4);
    int2* sorted    = (int2*)alloc((size_t)E * 8);
    float* B1       = (float*)alloc((size_t)n * D * 4); // agg output
    float* B2       = (float*)alloc((size_t)n * D * 4); // h1
    int* in_deg  = deg_buf;
    int* out_deg = deg_buf + n;

    int eb = (E + 255) / 256;
    int qn = (n + 3) / 4;                  // nodes per quad
    int ab = 8 * ((qn + 3) / 4);           // 8 XCD slots x groups of 4 nodes
    int gb = (n + GM - 1) / GM;

    hipMemsetAsync(deg_buf, 0, (size_t)2 * n * 4, stream);
    deg_kernel<<<eb, 256, 0, stream>>>(src, dst, in_deg, out_deg, E);
    scan_kernel<<<1, 1024, 0, stream>>>(in_deg, out_deg, row_start, cursor, norm_src, norm_dst, n);
    fill_kernel<<<eb, 256, 0, stream>>>(src, dst, ew, norm_src, cursor, sorted, E);

    // layer 1: agg x (norm_src folded in records) -> B1, gemm -> B2
    agg_kernel<<<ab, 256, 0, stream>>>(x, row_start, sorted, B1, n, qn);
    gemm_kernel<<<gb, 256, 0, stream>>>(B1, W0, b0, norm_dst, B2, n);
    // layer 2: agg B2 -> B1, gemm -> out
    agg_kernel<<<ab, 256, 0, stream>>>(B2, row_start, sorted, B1, n, qn);
    gemm_kernel<<<gb, 256, 0, stream>>>(B1, W1, b1, norm_dst, out, n);
}

// Round 5
// 190.855 us; speedup vs baseline: 1.3682x; 1.3682x over previous
//
#include <hip/hip_runtime.h>

#define D 128
#define NB 256          // counting-sort chunks (one block each)
#define Q 8             // quarters for the b-dimension scan
#define BQ (NB / Q)     // blocks per quarter = 32
#define NBINS_MAX 10016 // max nodes supported by LDS histogram (~40 KB)
#define GM 32           // gemm rows per block

// ---------------- fused per-chunk LDS histograms of dst and src ----------------
__global__ __launch_bounds__(256) void hist_kernel(const int* __restrict__ src, const int* __restrict__ dst,
                                                   int* __restrict__ pd, unsigned short* __restrict__ ps,
                                                   int E, int n) {
    __shared__ int hd[NBINS_MAX];
    __shared__ int hs[NBINS_MAX];
    int b = blockIdx.x, t = threadIdx.x;
    int chunk = (E + NB - 1) / NB;
    int e0 = b * chunk, e1 = min(e0 + chunk, E);
    for (int i = t; i < n; i += 256) { hd[i] = 0; hs[i] = 0; }
    __syncthreads();
    for (int e = e0 + t; e < e1; e += 256) {
        atomicAdd(&hd[dst[e]], 1);
        atomicAdd(&hs[src[e]], 1);
    }
    __syncthreads();
    for (int i = t; i < n; i += 256) {
        pd[(size_t)b * n + i] = hd[i];
        ps[(size_t)b * n + i] = (unsigned short)hs[i];
    }
}

// ---------------- within-quarter exclusive scan of pd along b (in place) ----------------
__global__ __launch_bounds__(256) void colscan_kernel(int* __restrict__ pd, const unsigned short* __restrict__ ps,
                                                      int* __restrict__ qtot_d, int* __restrict__ qtot_s, int n) {
    int bin = blockIdx.x * 256 + threadIdx.x;
    int q = blockIdx.y;
    if (bin >= n) return;
    int b0 = q * BQ;
    int run = 0, ssum = 0;
#pragma unroll 8
    for (int j = 0; j < BQ; ++j) {
        size_t idx = (size_t)(b0 + j) * n + bin;
        int v = pd[idx];
        pd[idx] = run;
        run += v;
        ssum += (int)ps[idx];
    }
    qtot_d[(size_t)q * n + bin] = run;
    qtot_s[(size_t)q * n + bin] = ssum;
}

// ---------------- per-bin: scan quarter totals -> bases; degrees -> norms ----------------
__global__ __launch_bounds__(256) void finalize_kernel(int* __restrict__ qtot_d /* becomes qbase */,
                                                       const int* __restrict__ qtot_s,
                                                       int* __restrict__ in_deg,
                                                       float* __restrict__ norm_src, float* __restrict__ norm_dst,
                                                       int n) {
    int bin = blockIdx.x * 256 + threadIdx.x;
    if (bin >= n) return;
    int run = 0;
#pragma unroll
    for (int q = 0; q < Q; ++q) {
        size_t i = (size_t)q * n + bin;
        int v = qtot_d[i];
        qtot_d[i] = run;
        run += v;
    }
    in_deg[bin] = run;
    norm_dst[bin] = rsqrtf(fmaxf((float)run, 1.0f));
    int tot = 0;
#pragma unroll
    for (int q = 0; q < Q; ++q) tot += qtot_s[(size_t)q * n + bin];
    norm_src[bin] = rsqrtf(fmaxf((float)tot, 1.0f));
}

// ---------------- exclusive scan of in_deg -> row_start (single block, LDS-staged) ----------------
__global__ __launch_bounds__(1024) void scan_kernel(const int* __restrict__ in_deg, int* __restrict__ row_start, int n) {
    __shared__ int buf[NBINS_MAX];
    __shared__ int part[1024];
    int t = threadIdx.x;
    for (int i = t; i < n; i += 1024) buf[i] = in_deg[i];
    __syncthreads();
    int ipt = (n + 1023) / 1024;
    int lo = min(t * ipt, n), hi = min(lo + ipt, n);
    int s = 0;
    for (int i = lo; i < hi; ++i) s += buf[i];
    part[t] = s;
    __syncthreads();
    for (int off = 1; off < 1024; off <<= 1) {
        int v = 0;
        if (t >= off) v = part[t - off];
        __syncthreads();
        if (t >= off) part[t] += v;
        __syncthreads();
    }
    int run = part[t] - s;
    for (int i = lo; i < hi; ++i) {
        int v = buf[i];
        buf[i] = run;
        run += v;
    }
    __syncthreads();
    for (int i = t; i < n; i += 1024) row_start[i] = buf[i];
    if (t == 0) row_start[n] = part[1023];
}

// ---------------- CSR fill: LDS cursor pre-seeded with absolute slot base ----------------
// Record weight = ew[e] * norm_src[src[e]]  (layer-invariant; folds the src-norm).
__global__ __launch_bounds__(256) void fill_kernel(const int* __restrict__ src, const int* __restrict__ dst,
                                                   const float* __restrict__ ew, const float* __restrict__ ns,
                                                   const int* __restrict__ row_start, const int* __restrict__ qbase,
                                                   const int* __restrict__ pd,
                                                   int2* __restrict__ sorted, int E, int n) {
    __shared__ int cursor[NBINS_MAX];
    int b = blockIdx.x, t = threadIdx.x;
    int q = b / BQ;
    int chunk = (E + NB - 1) / NB;
    int e0 = b * chunk, e1 = min(e0 + chunk, E);
    for (int i = t; i < n; i += 256)
        cursor[i] = row_start[i] + qbase[(size_t)q * n + i] + pd[(size_t)b * n + i];
    __syncthreads();
    for (int e = e0 + t; e < e1; e += 256) {
        int d = dst[e];
        int slot = atomicAdd(&cursor[d], 1);
        int s = src[e];
        int2 rec;
        rec.x = s;
        rec.y = __float_as_int(ew[e] * ns[s]);
        sorted[slot] = rec;
    }
}

// ---------------- XCD-partitioned aggregation, 16-deep software pipeline ----------------
// blockIdx%8 -> XCD slot. Slots 0-3 handle feature chunk [0,64), slots 4-7
// chunk [64,128); hot slice per XCD = n*256B = 2.56MB -> L2-resident.
// One wave per (node, chunk); lane = feature. 16 gathers in flight per wave,
// next batch's 8 record-int4s prefetched a full batch ahead (latency-bound fix).
// Edge consumption order is strictly sequential -> numerics identical to R1.
__global__ __launch_bounds__(256) void agg_kernel(const float* __restrict__ h, const int* __restrict__ row_start,
                                                  const int2* __restrict__ sorted, float* __restrict__ out,
                                                  int n, int qn) {
    int slot  = blockIdx.x & 7;
    int g     = blockIdx.x >> 3;
    int chunk = slot >> 2;         // 0 or 1
    int quad  = slot & 3;          // node quad
    int wave  = threadIdx.x >> 6;
    int lane  = threadIdx.x & 63;
    int node  = quad * qn + g * 4 + wave;
    int hiN   = min((quad + 1) * qn, n);
    if (node >= hiN) return;
    const float* hc = h + chunk * 64 + lane;
    int beg = __builtin_amdgcn_readfirstlane(row_start[node]);
    int end = __builtin_amdgcn_readfirstlane(row_start[node + 1]);
    float acc = 0.f;
    int s = beg;
    if (s < end && (s & 1)) {   // peel to even index -> 16B-aligned int4 record loads
        int2 rr = sorted[s];
        acc = fmaf(__int_as_float(rr.y), hc[rr.x << 7], acc);
        ++s;
    }
    int4 p0, p1, p2, p3, p4, p5, p6, p7;
    if (s + 16 <= end) {
        p0 = *(const int4*)(sorted + s);
        p1 = *(const int4*)(sorted + s + 2);
        p2 = *(const int4*)(sorted + s + 4);
        p3 = *(const int4*)(sorted + s + 6);
        p4 = *(const int4*)(sorted + s + 8);
        p5 = *(const int4*)(sorted + s + 10);
        p6 = *(const int4*)(sorted + s + 12);
        p7 = *(const int4*)(sorted + s + 14);
    }
    for (; s + 32 <= end; s += 16) {
        // prefetch next batch's records (independent of current gathers)
        int4 q0 = *(const int4*)(sorted + s + 16);
        int4 q1 = *(const int4*)(sorted + s + 18);
        int4 q2 = *(const int4*)(sorted + s + 20);
        int4 q3 = *(const int4*)(sorted + s + 22);
        int4 q4 = *(const int4*)(sorted + s + 24);
        int4 q5 = *(const int4*)(sorted + s + 26);
        int4 q6 = *(const int4*)(sorted + s + 28);
        int4 q7 = *(const int4*)(sorted + s + 30);
        float x0  = hc[p0.x << 7];
        float x1  = hc[p0.z << 7];
        float x2  = hc[p1.x << 7];
        float x3  = hc[p1.z << 7];
        float x4  = hc[p2.x << 7];
        float x5  = hc[p2.z << 7];
        float x6  = hc[p3.x << 7];
        float x7  = hc[p3.z << 7];
        float x8  = hc[p4.x << 7];
        float x9  = hc[p4.z << 7];
        float x10 = hc[p5.x << 7];
        float x11 = hc[p5.z << 7];
        float x12 = hc[p6.x << 7];
        float x13 = hc[p6.z << 7];
        float x14 = hc[p7.x << 7];
        float x15 = hc[p7.z << 7];
        acc = fmaf(__int_as_float(p0.y), x0,  acc);
        acc = fmaf(__int_as_float(p0.w), x1,  acc);
        acc = fmaf(__int_as_float(p1.y), x2,  acc);
        acc = fmaf(__int_as_float(p1.w), x3,  acc);
        acc = fmaf(__int_as_float(p2.y), x4,  acc);
        acc = fmaf(__int_as_float(p2.w), x5,  acc);
        acc = fmaf(__int_as_float(p3.y), x6,  acc);
        acc = fmaf(__int_as_float(p3.w), x7,  acc);
        acc = fmaf(__int_as_float(p4.y), x8,  acc);
        acc = fmaf(__int_as_float(p4.w), x9,  acc);
        acc = fmaf(__int_as_float(p5.y), x10, acc);
        acc = fmaf(__int_as_float(p5.w), x11, acc);
        acc = fmaf(__int_as_float(p6.y), x12, acc);
        acc = fmaf(__int_as_float(p6.w), x13, acc);
        acc = fmaf(__int_as_float(p7.y), x14, acc);
        acc = fmaf(__int_as_float(p7.w), x15, acc);
        p0 = q0; p1 = q1; p2 = q2; p3 = q3;
        p4 = q4; p5 = q5; p6 = q6; p7 = q7;
    }
    if (s + 16 <= end) {   // drain the pipelined batch
        float x0  = hc[p0.x << 7];
        float x1  = hc[p0.z << 7];
        float x2  = hc[p1.x << 7];
        float x3  = hc[p1.z << 7];
        float x4  = hc[p2.x << 7];
        float x5  = hc[p2.z << 7];
        float x6  = hc[p3.x << 7];
        float x7  = hc[p3.z << 7];
        float x8  = hc[p4.x << 7];
        float x9  = hc[p4.z << 7];
        float x10 = hc[p5.x << 7];
        float x11 = hc[p5.z << 7];
        float x12 = hc[p6.x << 7];
        float x13 = hc[p6.z << 7];
        float x14 = hc[p7.x << 7];
        float x15 = hc[p7.z << 7];
        acc = fmaf(__int_as_float(p0.y), x0,  acc);
        acc = fmaf(__int_as_float(p0.w), x1,  acc);
        acc = fmaf(__int_as_float(p1.y), x2,  acc);
        acc = fmaf(__int_as_float(p1.w), x3,  acc);
        acc = fmaf(__int_as_float(p2.y), x4,  acc);
        acc = fmaf(__int_as_float(p2.w), x5,  acc);
        acc = fmaf(__int_as_float(p3.y), x6,  acc);
        acc = fmaf(__int_as_float(p3.w), x7,  acc);
        acc = fmaf(__int_as_float(p4.y), x8,  acc);
        acc = fmaf(__int_as_float(p4.w), x9,  acc);
        acc = fmaf(__int_as_float(p5.y), x10, acc);
        acc = fmaf(__int_as_float(p5.w), x11, acc);
        acc = fmaf(__int_as_float(p6.y), x12, acc);
        acc = fmaf(__int_as_float(p6.w), x13, acc);
        acc = fmaf(__int_as_float(p7.y), x14, acc);
        acc = fmaf(__int_as_float(p7.w), x15, acc);
        s += 16;
    }
    if (s + 8 <= end) {   // 8-edge sub-batch (keeps tail <= 7)
        int4 a0 = *(const int4*)(sorted + s);
        int4 a1 = *(const int4*)(sorted + s + 2);
        int4 a2 = *(const int4*)(sorted + s + 4);
        int4 a3 = *(const int4*)(sorted + s + 6);
        float x0 = hc[a0.x << 7];
        float x1 = hc[a0.z << 7];
        float x2 = hc[a1.x << 7];
        float x3 = hc[a1.z << 7];
        float x4 = hc[a2.x << 7];
        float x5 = hc[a2.z << 7];
        float x6 = hc[a3.x << 7];
        float x7 = hc[a3.z << 7];
        acc = fmaf(__int_as_float(a0.y), x0, acc);
        acc = fmaf(__int_as_float(a0.w), x1, acc);
        acc = fmaf(__int_as_float(a1.y), x2, acc);
        acc = fmaf(__int_as_float(a1.w), x3, acc);
        acc = fmaf(__int_as_float(a2.y), x4, acc);
        acc = fmaf(__int_as_float(a2.w), x5, acc);
        acc = fmaf(__int_as_float(a3.y), x6, acc);
        acc = fmaf(__int_as_float(a3.w), x7, acc);
        s += 8;
    }
    for (; s + 2 <= end; s += 2) {
        int4 p = *(const int4*)(sorted + s);
        acc = fmaf(__int_as_float(p.y), hc[p.x << 7], acc);
        acc = fmaf(__int_as_float(p.w), hc[p.z << 7], acc);
    }
    if (s < end) {
        int2 rr = sorted[s];
        acc = fmaf(__int_as_float(rr.y), hc[rr.x << 7], acc);
    }
    out[((size_t)node << 7) + chunk * 64 + lane] = acc;
}

// ---------------- GEMM + epilogue: out = relu((A@W)*norm_dst[:,None] + b) ----------------
// 32-row tile, A staged TRANSPOSED in LDS (sAT[k][r], stride 34 -> broadcast-
// friendly float2 reads). 256 threads: tx=tid&15 (8 cols), ty=tid>>4 (2 rows).
__global__ __launch_bounds__(256) void gemm_kernel(const float* __restrict__ A, const float* __restrict__ W,
                                                   const float* __restrict__ bias, const float* __restrict__ norm_dst,
                                                   float* __restrict__ out, int n) {
    __shared__ __align__(16) float sAT[D][GM + 2];   // stride 34: float2 reads stay 8B-aligned
    int tid = threadIdx.x;
    int row0 = blockIdx.x * GM;
    for (int i = tid; i < GM * 32; i += 256) {
        int r = i >> 5;          // 0..31
        int kq = i & 31;         // k-quad
        int rr = row0 + r;
        float4 v = make_float4(0.f, 0.f, 0.f, 0.f);
        if (rr < n) v = *(const float4*)(A + (size_t)rr * D + kq * 4);
        sAT[kq * 4 + 0][r] = v.x;
        sAT[kq * 4 + 1][r] = v.y;
        sAT[kq * 4 + 2][r] = v.z;
        sAT[kq * 4 + 3][r] = v.w;
    }
    __syncthreads();
    int tx = tid & 15;
    int ty = tid >> 4;
    int c0 = tx * 8;
    int r0 = ty * 2;
    float acc0[8], acc1[8];
#pragma unroll
    for (int j = 0; j < 8; ++j) { acc0[j] = 0.f; acc1[j] = 0.f; }
    const float* Wk = W + c0;
#pragma unroll 4
    for (int k = 0; k < D; ++k) {
        float2 a = *(const float2*)&sAT[k][r0];
        float4 w0 = *(const float4*)(Wk);
        float4 w1 = *(const float4*)(Wk + 4);
        Wk += D;
        acc0[0] = fmaf(a.x, w0.x, acc0[0]);
        acc0[1] = fmaf(a.x, w0.y, acc0[1]);
        acc0[2] = fmaf(a.x, w0.z, acc0[2]);
        acc0[3] = fmaf(a.x, w0.w, acc0[3]);
        acc0[4] = fmaf(a.x, w1.x, acc0[4]);
        acc0[5] = fmaf(a.x, w1.y, acc0[5]);
        acc0[6] = fmaf(a.x, w1.z, acc0[6]);
        acc0[7] = fmaf(a.x, w1.w, acc0[7]);
        acc1[0] = fmaf(a.y, w0.x, acc1[0]);
        acc1[1] = fmaf(a.y, w0.y, acc1[1]);
        acc1[2] = fmaf(a.y, w0.z, acc1[2]);
        acc1[3] = fmaf(a.y, w0.w, acc1[3]);
        acc1[4] = fmaf(a.y, w1.x, acc1[4]);
        acc1[5] = fmaf(a.y, w1.y, acc1[5]);
        acc1[6] = fmaf(a.y, w1.z, acc1[6]);
        acc1[7] = fmaf(a.y, w1.w, acc1[7]);
    }
    int r = row0 + r0;
    if (r < n) {
        float nd = norm_dst[r];
        float4 o0, o1;
        o0.x = fmaxf(fmaf(acc0[0], nd, bias[c0 + 0]), 0.f);
        o0.y = fmaxf(fmaf(acc0[1], nd, bias[c0 + 1]), 0.f);
        o0.z = fmaxf(fmaf(acc0[2], nd, bias[c0 + 2]), 0.f);
        o0.w = fmaxf(fmaf(acc0[3], nd, bias[c0 + 3]), 0.f);
        o1.x = fmaxf(fmaf(acc0[4], nd, bias[c0 + 4]), 0.f);
        o1.y = fmaxf(fmaf(acc0[5], nd, bias[c0 + 5]), 0.f);
        o1.z = fmaxf(fmaf(acc0[6], nd, bias[c0 + 6]), 0.f);
        o1.w = fmaxf(fmaf(acc0[7], nd, bias[c0 + 7]), 0.f);
        *(float4*)(out + (size_t)r * D + c0) = o0;
        *(float4*)(out + (size_t)r * D + c0 + 4) = o1;
    }
    r = row0 + r0 + 1;
    if (r < n) {
        float nd = norm_dst[r];
        float4 o0, o1;
        o0.x = fmaxf(fmaf(acc1[0], nd, bias[c0 + 0]), 0.f);
        o0.y = fmaxf(fmaf(acc1[1], nd, bias[c0 + 1]), 0.f);
        o0.z = fmaxf(fmaf(acc1[2], nd, bias[c0 + 2]), 0.f);
        o0.w = fmaxf(fmaf(acc1[3], nd, bias[c0 + 3]), 0.f);
        o1.x = fmaxf(fmaf(acc1[4], nd, bias[c0 + 4]), 0.f);
        o1.y = fmaxf(fmaf(acc1[5], nd, bias[c0 + 5]), 0.f);
        o1.z = fmaxf(fmaf(acc1[6], nd, bias[c0 + 6]), 0.f);
        o1.w = fmaxf(fmaf(acc1[7], nd, bias[c0 + 7]), 0.f);
        *(float4*)(out + (size_t)r * D + c0) = o0;
        *(float4*)(out + (size_t)r * D + c0 + 4) = o1;
    }
}

extern "C" void kernel_launch(void* const* d_in, const int* in_sizes, int n_in,
                              void* d_out, int out_size, void* d_ws, size_t ws_size,
                              hipStream_t stream) {
    const float* x  = (const float*)d_in[0];
    const float* ew = (const float*)d_in[1];
    const float* W0 = (const float*)d_in[2];
    const float* b0 = (const float*)d_in[3];
    const float* W1 = (const float*)d_in[4];
    const float* b1 = (const float*)d_in[5];
    const int* src  = (const int*)d_in[6];
    const int* dst  = (const int*)d_in[7];
    float* out = (float*)d_out;

    int n = in_sizes[0] / D;   // 10000
    int E = in_sizes[6];       // 640000
    if (n <= 0 || E <= 0) return;

    char* ws = (char*)d_ws;
    size_t off = 0;
    auto alloc = [&](size_t bytes) -> void* {
        void* p = ws + off;
        off = (off + bytes + 255) & ~(size_t)255;
        return p;
    };
    int* row_start  = (int*)alloc(((size_t)n + 1) * 4);
    int* in_deg     = (int*)alloc((size_t)n * 4);
    float* norm_src = (float*)alloc((size_t)n * 4);
    float* norm_dst = (float*)alloc((size_t)n * 4);
    int* qtot_d     = (int*)alloc((size_t)Q * n * 4);   // becomes qbase in finalize
    int* qtot_s     = (int*)alloc((size_t)Q * n * 4);
    size_t sorted_bytes = (size_t)E * 8;
    size_t ps_bytes = (size_t)NB * n * 2;
    int2* sorted    = (int2*)alloc(sorted_bytes > ps_bytes ? sorted_bytes : ps_bytes);
    float* B1       = (float*)alloc((size_t)n * D * 4);   // agg output
    float* B2       = (float*)alloc((size_t)n * D * 4);   // h1
    // pd (NB*n ints = 10.24 MB) aliases B1+B2 (contiguous, both 256B-rounded);
    // consumed by fill_kernel before agg writes B1.
    int* pd = (int*)B1;
    // ps (NB*n ushorts) aliases sorted; consumed by colscan before fill writes sorted.
    unsigned short* ps = (unsigned short*)sorted;

    int nb = (n + 255) / 256;
    int qn = (n + 3) / 4;                  // nodes per quad
    int ab = 8 * ((qn + 3) / 4);           // 8 XCD slots x groups of 4 nodes
    int gb = (n + GM - 1) / GM;

    hist_kernel<<<NB, 256, 0, stream>>>(src, dst, pd, ps, E, n);
    colscan_kernel<<<dim3(nb, Q), 256, 0, stream>>>(pd, ps, qtot_d, qtot_s, n);
    finalize_kernel<<<nb, 256, 0, stream>>>(qtot_d, qtot_s, in_deg, norm_src, norm_dst, n);
    scan_kernel<<<1, 1024, 0, stream>>>(in_deg, row_start, n);
    fill_kernel<<<NB, 256, 0, stream>>>(src, dst, ew, norm_src, row_start, qtot_d, pd, sorted, E, n);

    // layer 1: agg x (norm_src folded in records) -> B1, gemm -> B2
    agg_kernel<<<ab, 256, 0, stream>>>(x, row_start, sorted, B1, n, qn);
    gemm_kernel<<<gb, 256, 0, stream>>>(B1, W0, b0, norm_dst, B2, n);
    // layer 2: agg B2 -> B1, gemm -> out
    agg_kernel<<<ab, 256, 0, stream>>>(B2, row_start, sorted, B1, n, qn);
    gemm_kernel<<<gb, 256, 0, stream>>>(B1, W1, b1, norm_dst, out, n);
}

// Round 6
// 188.480 us; speedup vs baseline: 1.3855x; 1.0126x over previous
//
#include <hip/hip_runtime.h>
#include <hip/hip_fp16.h>

#define D 128
#define NB 256          // counting-sort chunks (one block each)
#define Q 8             // quarters for the b-dimension scan
#define BQ (NB / Q)     // blocks per quarter = 32
#define NBINS_MAX 10016 // max nodes supported by LDS histogram (~40 KB)
#define GM 32           // gemm rows per block

// ---------------- cast x -> fp16 (once; gathers read half) ----------------
__global__ __launch_bounds__(256) void cast_kernel(const float* __restrict__ x, __half* __restrict__ xh, int total4) {
    int i = blockIdx.x * 256 + threadIdx.x;
    if (i >= total4) return;
    float4 v = *(const float4*)(x + (size_t)i * 4);
    __half2 a = __floats2half2_rn(v.x, v.y);
    __half2 b = __floats2half2_rn(v.z, v.w);
    *(__half2*)(xh + (size_t)i * 4) = a;
    *(__half2*)(xh + (size_t)i * 4 + 2) = b;
}

// ---------------- fused per-chunk LDS histograms of dst and src ----------------
__global__ __launch_bounds__(256) void hist_kernel(const int* __restrict__ src, const int* __restrict__ dst,
                                                   int* __restrict__ pd, unsigned short* __restrict__ ps,
                                                   int E, int n) {
    __shared__ int hd[NBINS_MAX];
    __shared__ int hs[NBINS_MAX];
    int b = blockIdx.x, t = threadIdx.x;
    int chunk = (E + NB - 1) / NB;
    int e0 = b * chunk, e1 = min(e0 + chunk, E);
    for (int i = t; i < n; i += 256) { hd[i] = 0; hs[i] = 0; }
    __syncthreads();
    for (int e = e0 + t; e < e1; e += 256) {
        atomicAdd(&hd[dst[e]], 1);
        atomicAdd(&hs[src[e]], 1);
    }
    __syncthreads();
    for (int i = t; i < n; i += 256) {
        pd[(size_t)b * n + i] = hd[i];
        ps[(size_t)b * n + i] = (unsigned short)hs[i];
    }
}

// ---------------- within-quarter exclusive scan of pd along b (in place) ----------------
__global__ __launch_bounds__(256) void colscan_kernel(int* __restrict__ pd, const unsigned short* __restrict__ ps,
                                                      int* __restrict__ qtot_d, int* __restrict__ qtot_s, int n) {
    int bin = blockIdx.x * 256 + threadIdx.x;
    int q = blockIdx.y;
    if (bin >= n) return;
    int b0 = q * BQ;
    int run = 0, ssum = 0;
#pragma unroll 8
    for (int j = 0; j < BQ; ++j) {
        size_t idx = (size_t)(b0 + j) * n + bin;
        int v = pd[idx];
        pd[idx] = run;
        run += v;
        ssum += (int)ps[idx];
    }
    qtot_d[(size_t)q * n + bin] = run;
    qtot_s[(size_t)q * n + bin] = ssum;
}

// ---------------- per-bin: scan quarter totals -> bases; degrees -> norms ----------------
__global__ __launch_bounds__(256) void finalize_kernel(int* __restrict__ qtot_d /* becomes qbase */,
                                                       const int* __restrict__ qtot_s,
                                                       int* __restrict__ in_deg,
                                                       float* __restrict__ norm_src, float* __restrict__ norm_dst,
                                                       int n) {
    int bin = blockIdx.x * 256 + threadIdx.x;
    if (bin >= n) return;
    int run = 0;
#pragma unroll
    for (int q = 0; q < Q; ++q) {
        size_t i = (size_t)q * n + bin;
        int v = qtot_d[i];
        qtot_d[i] = run;
        run += v;
    }
    in_deg[bin] = run;
    norm_dst[bin] = rsqrtf(fmaxf((float)run, 1.0f));
    int tot = 0;
#pragma unroll
    for (int q = 0; q < Q; ++q) tot += qtot_s[(size_t)q * n + bin];
    norm_src[bin] = rsqrtf(fmaxf((float)tot, 1.0f));
}

// ---------------- exclusive scan of in_deg -> row_start (single block, LDS-staged) ----------------
__global__ __launch_bounds__(1024) void scan_kernel(const int* __restrict__ in_deg, int* __restrict__ row_start, int n) {
    __shared__ int buf[NBINS_MAX];
    __shared__ int part[1024];
    int t = threadIdx.x;
    for (int i = t; i < n; i += 1024) buf[i] = in_deg[i];
    __syncthreads();
    int ipt = (n + 1023) / 1024;
    int lo = min(t * ipt, n), hi = min(lo + ipt, n);
    int s = 0;
    for (int i = lo; i < hi; ++i) s += buf[i];
    part[t] = s;
    __syncthreads();
    for (int off = 1; off < 1024; off <<= 1) {
        int v = 0;
        if (t >= off) v = part[t - off];
        __syncthreads();
        if (t >= off) part[t] += v;
        __syncthreads();
    }
    int run = part[t] - s;
    for (int i = lo; i < hi; ++i) {
        int v = buf[i];
        buf[i] = run;
        run += v;
    }
    __syncthreads();
    for (int i = t; i < n; i += 1024) row_start[i] = buf[i];
    if (t == 0) row_start[n] = part[1023];
}

// ---------------- CSR fill: LDS cursor pre-seeded with absolute slot base ----------------
// Record weight = ew[e] * norm_src[src[e]]  (layer-invariant; folds the src-norm).
__global__ __launch_bounds__(256) void fill_kernel(const int* __restrict__ src, const int* __restrict__ dst,
                                                   const float* __restrict__ ew, const float* __restrict__ ns,
                                                   const int* __restrict__ row_start, const int* __restrict__ qbase,
                                                   const int* __restrict__ pd,
                                                   int2* __restrict__ sorted, int E, int n) {
    __shared__ int cursor[NBINS_MAX];
    int b = blockIdx.x, t = threadIdx.x;
    int q = b / BQ;
    int chunk = (E + NB - 1) / NB;
    int e0 = b * chunk, e1 = min(e0 + chunk, E);
    for (int i = t; i < n; i += 256)
        cursor[i] = row_start[i] + qbase[(size_t)q * n + i] + pd[(size_t)b * n + i];
    __syncthreads();
    for (int e = e0 + t; e < e1; e += 256) {
        int d = dst[e];
        int slot = atomicAdd(&cursor[d], 1);
        int s = src[e];
        int2 rec;
        rec.x = s;
        rec.y = __float_as_int(ew[e] * ns[s]);
        sorted[slot] = rec;
    }
}

// ---------------- XCD-partitioned aggregation over fp16 features ----------------
// blockIdx%8 -> XCD slot. Slots 0-3 handle feature chunk [0,64), slots 4-7
// chunk [64,128); hot slice per XCD = n*128B = 1.28MB -> L2-resident.
// One wave per (node, chunk); lane = feature. Gathers are now 64x2B = 128B
// = 2 cache lines/edge (was 4): attacks the L2 line-throughput limit that
// R5's ILP-doubling null implicated. fp32 weights + fp32 accumulation.
__global__ __launch_bounds__(256) void agg_kernel(const __half* __restrict__ h, const int* __restrict__ row_start,
                                                  const int2* __restrict__ sorted, float* __restrict__ out,
                                                  int n, int qn) {
    int slot  = blockIdx.x & 7;
    int g     = blockIdx.x >> 3;
    int chunk = slot >> 2;         // 0 or 1
    int quad  = slot & 3;          // node quad
    int wave  = threadIdx.x >> 6;
    int lane  = threadIdx.x & 63;
    int node  = quad * qn + g * 4 + wave;
    int hiN   = min((quad + 1) * qn, n);
    if (node >= hiN) return;
    const __half* hc = h + chunk * 64 + lane;
    int beg = __builtin_amdgcn_readfirstlane(row_start[node]);
    int end = __builtin_amdgcn_readfirstlane(row_start[node + 1]);
    float acc = 0.f;
    int s = beg;
    if (s < end && (s & 1)) {   // peel to even index -> 16B-aligned int4 record loads
        int2 rr = sorted[s];
        acc = fmaf(__int_as_float(rr.y), __half2float(hc[(size_t)rr.x << 7]), acc);
        ++s;
    }
    int4 p0, p1, p2, p3, p4, p5, p6, p7;
    if (s + 16 <= end) {
        p0 = *(const int4*)(sorted + s);
        p1 = *(const int4*)(sorted + s + 2);
        p2 = *(const int4*)(sorted + s + 4);
        p3 = *(const int4*)(sorted + s + 6);
        p4 = *(const int4*)(sorted + s + 8);
        p5 = *(const int4*)(sorted + s + 10);
        p6 = *(const int4*)(sorted + s + 12);
        p7 = *(const int4*)(sorted + s + 14);
    }
    for (; s + 32 <= end; s += 16) {
        // prefetch next batch's records (independent of current gathers)
        int4 q0 = *(const int4*)(sorted + s + 16);
        int4 q1 = *(const int4*)(sorted + s + 18);
        int4 q2 = *(const int4*)(sorted + s + 20);
        int4 q3 = *(const int4*)(sorted + s + 22);
        int4 q4 = *(const int4*)(sorted + s + 24);
        int4 q5 = *(const int4*)(sorted + s + 26);
        int4 q6 = *(const int4*)(sorted + s + 28);
        int4 q7 = *(const int4*)(sorted + s + 30);
        __half x0  = hc[(size_t)p0.x << 7];
        __half x1  = hc[(size_t)p0.z << 7];
        __half x2  = hc[(size_t)p1.x << 7];
        __half x3  = hc[(size_t)p1.z << 7];
        __half x4  = hc[(size_t)p2.x << 7];
        __half x5  = hc[(size_t)p2.z << 7];
        __half x6  = hc[(size_t)p3.x << 7];
        __half x7  = hc[(size_t)p3.z << 7];
        __half x8  = hc[(size_t)p4.x << 7];
        __half x9  = hc[(size_t)p4.z << 7];
        __half x10 = hc[(size_t)p5.x << 7];
        __half x11 = hc[(size_t)p5.z << 7];
        __half x12 = hc[(size_t)p6.x << 7];
        __half x13 = hc[(size_t)p6.z << 7];
        __half x14 = hc[(size_t)p7.x << 7];
        __half x15 = hc[(size_t)p7.z << 7];
        acc = fmaf(__int_as_float(p0.y), __half2float(x0),  acc);
        acc = fmaf(__int_as_float(p0.w), __half2float(x1),  acc);
        acc = fmaf(__int_as_float(p1.y), __half2float(x2),  acc);
        acc = fmaf(__int_as_float(p1.w), __half2float(x3),  acc);
        acc = fmaf(__int_as_float(p2.y), __half2float(x4),  acc);
        acc = fmaf(__int_as_float(p2.w), __half2float(x5),  acc);
        acc = fmaf(__int_as_float(p3.y), __half2float(x6),  acc);
        acc = fmaf(__int_as_float(p3.w), __half2float(x7),  acc);
        acc = fmaf(__int_as_float(p4.y), __half2float(x8),  acc);
        acc = fmaf(__int_as_float(p4.w), __half2float(x9),  acc);
        acc = fmaf(__int_as_float(p5.y), __half2float(x10), acc);
        acc = fmaf(__int_as_float(p5.w), __half2float(x11), acc);
        acc = fmaf(__int_as_float(p6.y), __half2float(x12), acc);
        acc = fmaf(__int_as_float(p6.w), __half2float(x13), acc);
        acc = fmaf(__int_as_float(p7.y), __half2float(x14), acc);
        acc = fmaf(__int_as_float(p7.w), __half2float(x15), acc);
        p0 = q0; p1 = q1; p2 = q2; p3 = q3;
        p4 = q4; p5 = q5; p6 = q6; p7 = q7;
    }
    if (s + 16 <= end) {   // drain the pipelined batch
        acc = fmaf(__int_as_float(p0.y), __half2float(hc[(size_t)p0.x << 7]), acc);
        acc = fmaf(__int_as_float(p0.w), __half2float(hc[(size_t)p0.z << 7]), acc);
        acc = fmaf(__int_as_float(p1.y), __half2float(hc[(size_t)p1.x << 7]), acc);
        acc = fmaf(__int_as_float(p1.w), __half2float(hc[(size_t)p1.z << 7]), acc);
        acc = fmaf(__int_as_float(p2.y), __half2float(hc[(size_t)p2.x << 7]), acc);
        acc = fmaf(__int_as_float(p2.w), __half2float(hc[(size_t)p2.z << 7]), acc);
        acc = fmaf(__int_as_float(p3.y), __half2float(hc[(size_t)p3.x << 7]), acc);
        acc = fmaf(__int_as_float(p3.w), __half2float(hc[(size_t)p3.z << 7]), acc);
        acc = fmaf(__int_as_float(p4.y), __half2float(hc[(size_t)p4.x << 7]), acc);
        acc = fmaf(__int_as_float(p4.w), __half2float(hc[(size_t)p4.z << 7]), acc);
        acc = fmaf(__int_as_float(p5.y), __half2float(hc[(size_t)p5.x << 7]), acc);
        acc = fmaf(__int_as_float(p5.w), __half2float(hc[(size_t)p5.z << 7]), acc);
        acc = fmaf(__int_as_float(p6.y), __half2float(hc[(size_t)p6.x << 7]), acc);
        acc = fmaf(__int_as_float(p6.w), __half2float(hc[(size_t)p6.z << 7]), acc);
        acc = fmaf(__int_as_float(p7.y), __half2float(hc[(size_t)p7.x << 7]), acc);
        acc = fmaf(__int_as_float(p7.w), __half2float(hc[(size_t)p7.z << 7]), acc);
        s += 16;
    }
    if (s + 8 <= end) {   // 8-edge sub-batch (keeps tail <= 7)
        int4 a0 = *(const int4*)(sorted + s);
        int4 a1 = *(const int4*)(sorted + s + 2);
        int4 a2 = *(const int4*)(sorted + s + 4);
        int4 a3 = *(const int4*)(sorted + s + 6);
        acc = fmaf(__int_as_float(a0.y), __half2float(hc[(size_t)a0.x << 7]), acc);
        acc = fmaf(__int_as_float(a0.w), __half2float(hc[(size_t)a0.z << 7]), acc);
        acc = fmaf(__int_as_float(a1.y), __half2float(hc[(size_t)a1.x << 7]), acc);
        acc = fmaf(__int_as_float(a1.w), __half2float(hc[(size_t)a1.z << 7]), acc);
        acc = fmaf(__int_as_float(a2.y), __half2float(hc[(size_t)a2.x << 7]), acc);
        acc = fmaf(__int_as_float(a2.w), __half2float(hc[(size_t)a2.z << 7]), acc);
        acc = fmaf(__int_as_float(a3.y), __half2float(hc[(size_t)a3.x << 7]), acc);
        acc = fmaf(__int_as_float(a3.w), __half2float(hc[(size_t)a3.z << 7]), acc);
        s += 8;
    }
    for (; s + 2 <= end; s += 2) {
        int4 p = *(const int4*)(sorted + s);
        acc = fmaf(__int_as_float(p.y), __half2float(hc[(size_t)p.x << 7]), acc);
        acc = fmaf(__int_as_float(p.w), __half2float(hc[(size_t)p.z << 7]), acc);
    }
    if (s < end) {
        int2 rr = sorted[s];
        acc = fmaf(__int_as_float(rr.y), __half2float(hc[(size_t)rr.x << 7]), acc);
    }
    out[((size_t)node << 7) + chunk * 64 + lane] = acc;
}

// ---------------- GEMM + epilogue: out = relu((A@W)*norm_dst[:,None] + b) ----------------
// 32-row tile, A staged TRANSPOSED in LDS. HALF_OUT=1 writes fp16 (feeds the
// next layer's gathers); HALF_OUT=0 writes fp32 (final output).
template <int HALF_OUT>
__global__ __launch_bounds__(256) void gemm_kernel(const float* __restrict__ A, const float* __restrict__ W,
                                                   const float* __restrict__ bias, const float* __restrict__ norm_dst,
                                                   float* __restrict__ out, __half* __restrict__ out_h, int n) {
    __shared__ __align__(16) float sAT[D][GM + 2];   // stride 34: float2 reads stay 8B-aligned
    int tid = threadIdx.x;
    int row0 = blockIdx.x * GM;
    for (int i = tid; i < GM * 32; i += 256) {
        int r = i >> 5;          // 0..31
        int kq = i & 31;         // k-quad
        int rr = row0 + r;
        float4 v = make_float4(0.f, 0.f, 0.f, 0.f);
        if (rr < n) v = *(const float4*)(A + (size_t)rr * D + kq * 4);
        sAT[kq * 4 + 0][r] = v.x;
        sAT[kq * 4 + 1][r] = v.y;
        sAT[kq * 4 + 2][r] = v.z;
        sAT[kq * 4 + 3][r] = v.w;
    }
    __syncthreads();
    int tx = tid & 15;
    int ty = tid >> 4;
    int c0 = tx * 8;
    int r0 = ty * 2;
    float acc0[8], acc1[8];
#pragma unroll
    for (int j = 0; j < 8; ++j) { acc0[j] = 0.f; acc1[j] = 0.f; }
    const float* Wk = W + c0;
#pragma unroll 4
    for (int k = 0; k < D; ++k) {
        float2 a = *(const float2*)&sAT[k][r0];
        float4 w0 = *(const float4*)(Wk);
        float4 w1 = *(const float4*)(Wk + 4);
        Wk += D;
        acc0[0] = fmaf(a.x, w0.x, acc0[0]);
        acc0[1] = fmaf(a.x, w0.y, acc0[1]);
        acc0[2] = fmaf(a.x, w0.z, acc0[2]);
        acc0[3] = fmaf(a.x, w0.w, acc0[3]);
        acc0[4] = fmaf(a.x, w1.x, acc0[4]);
        acc0[5] = fmaf(a.x, w1.y, acc0[5]);
        acc0[6] = fmaf(a.x, w1.z, acc0[6]);
        acc0[7] = fmaf(a.x, w1.w, acc0[7]);
        acc1[0] = fmaf(a.y, w0.x, acc1[0]);
        acc1[1] = fmaf(a.y, w0.y, acc1[1]);
        acc1[2] = fmaf(a.y, w0.z, acc1[2]);
        acc1[3] = fmaf(a.y, w0.w, acc1[3]);
        acc1[4] = fmaf(a.y, w1.x, acc1[4]);
        acc1[5] = fmaf(a.y, w1.y, acc1[5]);
        acc1[6] = fmaf(a.y, w1.z, acc1[6]);
        acc1[7] = fmaf(a.y, w1.w, acc1[7]);
    }
#pragma unroll 2
    for (int rr = 0; rr < 2; ++rr) {
        int r = row0 + r0 + rr;
        if (r >= n) continue;
        float* acc = rr ? acc1 : acc0;
        float nd = norm_dst[r];
        float o[8];
#pragma unroll
        for (int j = 0; j < 8; ++j) o[j] = fmaxf(fmaf(acc[j], nd, bias[c0 + j]), 0.f);
        if (HALF_OUT) {
            __half2 h0 = __floats2half2_rn(o[0], o[1]);
            __half2 h1 = __floats2half2_rn(o[2], o[3]);
            __half2 h2 = __floats2half2_rn(o[4], o[5]);
            __half2 h3 = __floats2half2_rn(o[6], o[7]);
            __half* p = out_h + (size_t)r * D + c0;
            *(__half2*)(p + 0) = h0;
            *(__half2*)(p + 2) = h1;
            *(__half2*)(p + 4) = h2;
            *(__half2*)(p + 6) = h3;
        } else {
            float4 o0 = make_float4(o[0], o[1], o[2], o[3]);
            float4 o1 = make_float4(o[4], o[5], o[6], o[7]);
            *(float4*)(out + (size_t)r * D + c0) = o0;
            *(float4*)(out + (size_t)r * D + c0 + 4) = o1;
        }
    }
}

extern "C" void kernel_launch(void* const* d_in, const int* in_sizes, int n_in,
                              void* d_out, int out_size, void* d_ws, size_t ws_size,
                              hipStream_t stream) {
    const float* x  = (const float*)d_in[0];
    const float* ew = (const float*)d_in[1];
    const float* W0 = (const float*)d_in[2];
    const float* b0 = (const float*)d_in[3];
    const float* W1 = (const float*)d_in[4];
    const float* b1 = (const float*)d_in[5];
    const int* src  = (const int*)d_in[6];
    const int* dst  = (const int*)d_in[7];
    float* out = (float*)d_out;

    int n = in_sizes[0] / D;   // 10000
    int E = in_sizes[6];       // 640000
    if (n <= 0 || E <= 0) return;

    char* ws = (char*)d_ws;
    size_t off = 0;
    auto alloc = [&](size_t bytes) -> void* {
        void* p = ws + off;
        off = (off + bytes + 255) & ~(size_t)255;
        return p;
    };
    int* row_start  = (int*)alloc(((size_t)n + 1) * 4);
    int* in_deg     = (int*)alloc((size_t)n * 4);
    float* norm_src = (float*)alloc((size_t)n * 4);
    float* norm_dst = (float*)alloc((size_t)n * 4);
    int* qtot_d     = (int*)alloc((size_t)Q * n * 4);   // becomes qbase in finalize
    int* qtot_s     = (int*)alloc((size_t)Q * n * 4);
    int2* sorted    = (int2*)alloc((size_t)E * 8);
    int* pd         = (int*)alloc((size_t)NB * n * 4);
    unsigned short* ps = (unsigned short*)alloc((size_t)NB * n * 2);
    float* B1       = (float*)alloc((size_t)n * D * 4); // agg output (fp32)
    __half* xh      = (__half*)alloc((size_t)n * D * 2); // x as fp16
    __half* B2h     = (__half*)alloc((size_t)n * D * 2); // h1 as fp16

    int nb = (n + 255) / 256;
    int qn = (n + 3) / 4;                  // nodes per quad
    int ab = 8 * ((qn + 3) / 4);           // 8 XCD slots x groups of 4 nodes
    int gb = (n + GM - 1) / GM;
    int cb = ((n * D / 4) + 255) / 256;

    cast_kernel<<<cb, 256, 0, stream>>>(x, xh, n * D / 4);
    hist_kernel<<<NB, 256, 0, stream>>>(src, dst, pd, ps, E, n);
    colscan_kernel<<<dim3(nb, Q), 256, 0, stream>>>(pd, ps, qtot_d, qtot_s, n);
    finalize_kernel<<<nb, 256, 0, stream>>>(qtot_d, qtot_s, in_deg, norm_src, norm_dst, n);
    scan_kernel<<<1, 1024, 0, stream>>>(in_deg, row_start, n);
    fill_kernel<<<NB, 256, 0, stream>>>(src, dst, ew, norm_src, row_start, qtot_d, pd, sorted, E, n);

    // layer 1: agg xh -> B1 (fp32), gemm -> B2h (fp16)
    agg_kernel<<<ab, 256, 0, stream>>>(xh, row_start, sorted, B1, n, qn);
    gemm_kernel<1><<<gb, 256, 0, stream>>>(B1, W0, b0, norm_dst, nullptr, B2h, n);
    // layer 2: agg B2h -> B1, gemm -> out (fp32)
    agg_kernel<<<ab, 256, 0, stream>>>(B2h, row_start, sorted, B1, n, qn);
    gemm_kernel<0><<<gb, 256, 0, stream>>>(B1, W1, b1, norm_dst, out, nullptr, n);
}